// Round 6
// baseline (151.347 us; speedup 1.0000x reference)
//
#include <hip/hip_runtime.h>
#include <math.h>

#define IN_F   1024
#define OUT_F  1024
#define TASK_D 256
#define RANK   8
#define HID    64
// SCALING = ALPHA / RANK = 1.0 (identity)

__device__ __forceinline__ float gelu_exact(float v) {
    return 0.5f * v * (1.0f + erff(v * 0.70710678118654752f));
}

// ---------------------------------------------------------------------------
// Kernel 1 (v6): generate LoRA tables, 2x parallelism vs v5.
// 512 blocks x 256 threads. Blocks 0..255 -> gen_a, 256..511 -> gen_b.
// Each block: redundantly computes h[4][64] (cheap, W1 L2-cached), then
// 32 W2 rows/block, 8 threads/row (each dots 8 of 64 hidden dims),
// 3-stage shuffle reduce, thread q==0 writes the 4 task values.
//   vec_a_t : [4][RANK][OUT_F]  (TRANSPOSED: a_t[t][r][o] = a[t][o][r])
//   vec_b   : [4][RANK][IN_F]   (natural Wb2 row order)
// ---------------------------------------------------------------------------
__global__ __launch_bounds__(256) void gen_kernel(
    const float* __restrict__ task_emb,
    const float* __restrict__ Wa1, const float* __restrict__ ba1,
    const float* __restrict__ Wa2, const float* __restrict__ ba2,
    const float* __restrict__ Wb1, const float* __restrict__ bb1,
    const float* __restrict__ Wb2, const float* __restrict__ bb2,
    float* __restrict__ vec_a_t, float* __restrict__ vec_b)
{
    const int gen = blockIdx.x >> 8;             // 0 -> a, 1 -> b
    const int blk = blockIdx.x & 255;            // 256 blocks per generator
    const float* __restrict__ W1 = gen ? Wb1 : Wa1;
    const float* __restrict__ b1 = gen ? bb1 : ba1;
    const float* __restrict__ W2 = gen ? Wb2 : Wa2;
    const float* __restrict__ b2 = gen ? bb2 : ba2;

    __shared__ float hs[4][HID];
    {
        const int j = threadIdx.x >> 2;          // hidden unit 0..63
        const int t = threadIdx.x & 3;           // task 0..3
        const float4* te = (const float4*)(task_emb + t * TASK_D);
        const float4* w  = (const float4*)(W1 + j * TASK_D);
        float acc = 0.f;
        #pragma unroll
        for (int d = 0; d < TASK_D / 4; ++d) {
            float4 a = te[d], b = w[d];
            acc += a.x * b.x + a.y * b.y + a.z * b.z + a.w * b.w;
        }
        hs[t][j] = gelu_exact(acc + b1[j]);
    }
    __syncthreads();

    const int lrow = threadIdx.x >> 3;           // 0..31  (W2 row within block)
    const int q    = threadIdx.x & 7;            // eighth of the 64 hidden dims
    const int o    = blk * 32 + lrow;            // W2 row 0..8191

    const float4* w2 = (const float4*)(W2 + (size_t)o * HID + q * 8);
    float acc0 = 0.f, acc1 = 0.f, acc2 = 0.f, acc3 = 0.f;
    #pragma unroll
    for (int k = 0; k < 2; ++k) {
        float4 w = w2[k];
        const int kb = q * 8 + k * 4;
        acc0 += hs[0][kb] * w.x + hs[0][kb+1] * w.y + hs[0][kb+2] * w.z + hs[0][kb+3] * w.w;
        acc1 += hs[1][kb] * w.x + hs[1][kb+1] * w.y + hs[1][kb+2] * w.z + hs[1][kb+3] * w.w;
        acc2 += hs[2][kb] * w.x + hs[2][kb+1] * w.y + hs[2][kb+2] * w.z + hs[2][kb+3] * w.w;
        acc3 += hs[3][kb] * w.x + hs[3][kb+1] * w.y + hs[3][kb+2] * w.z + hs[3][kb+3] * w.w;
    }
    // reduce across the 8 threads (adjacent lanes) of this row
    #pragma unroll
    for (int off = 1; off <= 4; off <<= 1) {
        acc0 += __shfl_xor(acc0, off, 64);
        acc1 += __shfl_xor(acc1, off, 64);
        acc2 += __shfl_xor(acc2, off, 64);
        acc3 += __shfl_xor(acc3, off, 64);
    }
    if (q == 0) {
        const float bb = b2[o];
        float v[4] = { acc0 + bb, acc1 + bb, acc2 + bb, acc3 + bb };
        if (gen == 0) {
            const int oo = o >> 3, r = o & 7;    // vec_a row o -> (out oo, rank r)
            #pragma unroll
            for (int t = 0; t < 4; ++t)
                vec_a_t[t * (RANK * OUT_F) + r * OUT_F + oo] = v[t];
        } else {
            #pragma unroll
            for (int t = 0; t < 4; ++t)
                vec_b[t * (RANK * IN_F) + o] = v[t];
        }
    }
}

// ---------------------------------------------------------------------------
// Kernel 2 (v6): fused apply, best-of-v4/v5 structure. 2048 blocks x 256 thr,
// 4 rows per block, task-pure blocks.
//   phase 1 (row-per-wave): wave i dots row i against the b-table
//     (32 L1/L2 table loads + 4 hoisted HBM x loads), 6-stage butterfly,
//     lane 0 -> 32 B of LDS.
//   phase 2 (column-per-thread): thread tid owns column o=tid*4 for all 4
//     rows; 8 a-table loads amortized over 4 rows (8 table-loads/row vs
//     v3's 64), tmp read from LDS broadcast, zero cross-lane ops.
// VGPR target <=84 (__launch_bounds__(256,6)) -> ~24 waves/CU.
// Only 128 B LDS; 2 kernel launches total (v5's 3rd launch gap removed).
// ---------------------------------------------------------------------------
__global__ __launch_bounds__(256, 6) void apply_kernel(
    const float* __restrict__ x, const float* __restrict__ base_out,
    const float* __restrict__ vec_a_t, const float* __restrict__ vec_b,
    float* __restrict__ out, int blocks_per_task)
{
    const int t    = blockIdx.x / blocks_per_task;   // task 0..3
    const int g    = blockIdx.x % blocks_per_task;   // group within task
    const int wave = threadIdx.x >> 6;
    const int ln   = threadIdx.x & 63;

    __shared__ float tmps[4][RANK];

    // ---- phase 1: this wave's row ----------------------------------------
    {
        const int row = t + 4 * (g * 4 + wave);
        const float* __restrict__ xr = x + (size_t)row * IN_F;
        const float* __restrict__ bt = vec_b + (size_t)t * (RANK * IN_F);

        float4 xv[4];
        #pragma unroll
        for (int c = 0; c < 4; ++c)
            xv[c] = *(const float4*)(xr + c * 256 + ln * 4);

        float acc[RANK];
        #pragma unroll
        for (int r = 0; r < RANK; ++r) acc[r] = 0.f;

        #pragma unroll
        for (int c = 0; c < 4; ++c) {
            const int k = c * 256 + ln * 4;
            #pragma unroll
            for (int r = 0; r < RANK; ++r) {
                const float4 bv = *(const float4*)(bt + r * IN_F + k);
                acc[r] += xv[c].x * bv.x + xv[c].y * bv.y
                        + xv[c].z * bv.z + xv[c].w * bv.w;
            }
        }

        #pragma unroll
        for (int off = 1; off <= 32; off <<= 1) {
            #pragma unroll
            for (int r = 0; r < RANK; ++r)
                acc[r] += __shfl_xor(acc[r], off, 64);
        }

        if (ln == 0) {
            #pragma unroll
            for (int r = 0; r < RANK; ++r)
                tmps[wave][r] = acc[r];             // static indices only
        }
    }
    __syncthreads();

    // ---- phase 2: this thread's column across all 4 rows -----------------
    const int o = threadIdx.x * 4;
    const float* __restrict__ at = vec_a_t + (size_t)t * (RANK * OUT_F);

    float4 af[RANK];
    #pragma unroll
    for (int r = 0; r < RANK; ++r)
        af[r] = *(const float4*)(at + r * OUT_F + o);

    float4 bo[4];
    #pragma unroll
    for (int i = 0; i < 4; ++i) {
        const int row = t + 4 * (g * 4 + i);
        bo[i] = *(const float4*)(base_out + (size_t)row * OUT_F + o);
    }

    #pragma unroll
    for (int i = 0; i < 4; ++i) {
        const int row = t + 4 * (g * 4 + i);
        float4 rv = bo[i];
        #pragma unroll
        for (int r = 0; r < RANK; ++r) {
            const float s = tmps[i][r];             // LDS broadcast read
            rv.x += s * af[r].x;
            rv.y += s * af[r].y;
            rv.z += s * af[r].z;
            rv.w += s * af[r].w;
        }
        *(float4*)(out + (size_t)row * OUT_F + o) = rv;
    }
}

extern "C" void kernel_launch(void* const* d_in, const int* in_sizes, int n_in,
                              void* d_out, int out_size, void* d_ws, size_t ws_size,
                              hipStream_t stream) {
    const float* x        = (const float*)d_in[0];
    const float* base_out = (const float*)d_in[1];
    const float* task_emb = (const float*)d_in[2];
    const float* Wa1      = (const float*)d_in[3];
    const float* ba1      = (const float*)d_in[4];
    const float* Wa2      = (const float*)d_in[5];
    const float* ba2      = (const float*)d_in[6];
    const float* Wb1      = (const float*)d_in[7];
    const float* bb1      = (const float*)d_in[8];
    const float* Wb2      = (const float*)d_in[9];
    const float* bb2      = (const float*)d_in[10];
    float* out = (float*)d_out;

    float* vec_a_t = (float*)d_ws;                        // 4*8192 floats
    float* vec_b   = vec_a_t + 4 * RANK * OUT_F;          // 4*8192 floats

    const int b_eff = in_sizes[0] / IN_F;                 // 8192

    gen_kernel<<<512, 256, 0, stream>>>(task_emb, Wa1, ba1, Wa2, ba2,
                                        Wb1, bb1, Wb2, bb2, vec_a_t, vec_b);

    const int nblk = b_eff / 4;                           // 2048 blocks, 4 rows each
    apply_kernel<<<nblk, 256, 0, stream>>>(x, base_out, vec_a_t, vec_b, out,
                                           nblk / 4);
}